// Round 2
// baseline (445.001 us; speedup 1.0000x reference)
//
#include <hip/hip_runtime.h>

// AdaptiveLayer: per-(b,f) sequential scan over T.
//   out[b,t,f] = max(x[b,t,f] - adapt, 0)
//   adapt      = (adapt + 0.1*out) * 0.9
// x: [B=32, T=512, F=4096] f32.
//
// R2: T-chunked parallel scan with warm-up redundancy.
// The recurrence is a contraction (|d adapt'/d adapt| <= 0.9), so a chunk
// starting from the t=0 initial state and warmed up over WARM=96 preceding
// steps converges to the true state within 0.9^96 ~= 4e-5 (threshold 0.1).
// CHUNKS=4 -> 524288 threads = 32 waves/CU (full occupancy) vs 2 waves/SIMD
// in R1 (latency-bound at 442 us).
// Traffic: 419 MB read + 268 MB write -> ~109 us roofline at 6.3 TB/s.

#define AB 32
#define AT 512
#define AF 4096
#define CHUNKS 4
#define CLEN (AT / CHUNKS)   // 128
#define WARM 96              // 0.9^96 ~= 4e-5 contraction of state error

__global__ __launch_bounds__(256, 8) void AdaptiveLayer_kernel(
    const float* __restrict__ x,
    const float* __restrict__ adaptation,
    float* __restrict__ out) {
    // tid = (c*B + b)*F + f : consecutive lanes -> consecutive f (coalesced).
    const int tid = blockIdx.x * blockDim.x + threadIdx.x;
    const int f  = tid & (AF - 1);
    const int cb = tid >> 12;            // c*B + b
    const int b  = cb & (AB - 1);
    const int c  = cb >> 5;              // log2(B)=5

    float adapt = adaptation[f];         // state at t=0 (broadcast over b)

    const size_t base = (size_t)b * (size_t)AT * (size_t)AF + (size_t)f;
    const float* __restrict__ xp = x + base;
    float* __restrict__ op = out + base;

    const int t0 = c * CLEN;

    // Warm-up: run the recurrence over the WARM steps preceding this chunk
    // (reads only, no writes) to converge adapt. Chunk 0 needs none.
    if (c > 0) {
        #pragma unroll 1
        for (int t = t0 - WARM; t < t0; t += 8) {   // WARM = 96 = 12*8
            float v[8];
            #pragma unroll
            for (int j = 0; j < 8; ++j) v[j] = xp[(size_t)(t + j) * AF];
            #pragma unroll
            for (int j = 0; j < 8; ++j) {
                float o = fmaxf(v[j] - adapt, 0.0f);
                adapt = (adapt + 0.1f * o) * 0.9f;
            }
        }
    }

    // Main chunk: compute and write outputs for t in [t0, t0+CLEN).
    #pragma unroll 1
    for (int t = t0; t < t0 + CLEN; t += 8) {
        float v[8];
        #pragma unroll
        for (int j = 0; j < 8; ++j) v[j] = xp[(size_t)(t + j) * AF];
        #pragma unroll
        for (int j = 0; j < 8; ++j) {
            float o = fmaxf(v[j] - adapt, 0.0f);
            // Nontemporal: 268 MB write stream, no reuse — keep out of L2.
            __builtin_nontemporal_store(o, &op[(size_t)(t + j) * AF]);
            adapt = (adapt + 0.1f * o) * 0.9f;
        }
    }
}

extern "C" void kernel_launch(void* const* d_in, const int* in_sizes, int n_in,
                              void* d_out, int out_size, void* d_ws, size_t ws_size,
                              hipStream_t stream) {
    const float* x          = (const float*)d_in[0];   // [B, T, F]
    const float* adaptation = (const float*)d_in[1];   // [1, F]
    float* out              = (float*)d_out;           // [B, T, F]

    const int n_threads = AB * AF * CHUNKS;            // 524288
    const int block = 256;
    const int grid = n_threads / block;                // 2048 blocks

    AdaptiveLayer_kernel<<<grid, block, 0, stream>>>(x, adaptation, out);
}